// Round 8
// baseline (214.342 us; speedup 1.0000x reference)
//
#include <hip/hip_runtime.h>

#define N_NODES 100000
#define N_EDGES 1600000
#define D 64
#define NB 196            // coarse buckets: nodes >> 9 (512 nodes each)
#define NR 8              // tail replicas per bucket (r = blockIdx&7 ~ XCD-aligned)
#define CAPB_R 1280       // per-(bucket,replica) capacity
#define LCAP 64           // per-node LDS CSR slots (dual-ended)
#define SRC_MASK 0x1FFFF  // 17 bits
#define NBB 782           // bucket-phase blocks in prep kernel

typedef unsigned int u32;
typedef short bfrag8 __attribute__((ext_vector_type(8)));   // 8 bf16 (4 VGPRs)
typedef float f32x4 __attribute__((ext_vector_type(4)));    // MFMA accumulator

// Workspace (~46.5 MB <= proven 51.2 MB):
//   bcnt:    int[2048]                8 KB     (zeroed per launch)
//   buckets: int[NB*NR*CAPB_R]        8.03 MB  entry = src | g<<17 | (d&511)<<18
//   X:       u32[N_NODES*96]         38.4 MB   packed bf16 pairs:
//              cols 0..31 = h, 32..63 = seg group0, 64..95 = seg group1
//   Wc:      u32[64*96]              24.6 KB   packed bf16 Wcomb[j][k]

__device__ inline u32 pk_bf16(float lo, float hi) {
    u32 a = __float_as_uint(lo);
    a = (a + 0x7fffu + ((a >> 16) & 1u)) >> 16;
    u32 b = __float_as_uint(hi);
    b = (b + 0x7fffu + ((b >> 16) & 1u)) & 0xffff0000u;
    return a | b;
}

// ---------------------------------------------------------------------------
// Fused prep: blocks [0,782) bucket edges; [782, 13282) transcode h -> X;
// block 13282 builds Wcomb. Overlaps the scatter-bound and BW-bound phases.
// ---------------------------------------------------------------------------
__global__ __launch_bounds__(256) void prep(const float* __restrict__ h,
                                            const float* __restrict__ W_self,
                                            const float* __restrict__ W_groups,
                                            const int* __restrict__ src,
                                            const int* __restrict__ dst,
                                            const int* __restrict__ grp,
                                            int* __restrict__ bcnt,
                                            int* __restrict__ buckets,
                                            u32* __restrict__ X,
                                            u32* __restrict__ Wc) {
    __shared__ int hist[NB];
    __shared__ int gbase[NB];
    const int tid = threadIdx.x;
    const int bx = blockIdx.x;

    if (bx < NBB) {
        // ---- bucket phase ----
        const int r = bx & (NR - 1);
        for (int b = tid; b < NB; b += 256) hist[b] = 0;
        __syncthreads();

        int ent[8], bkt[8], rnk[8];
        const int e0 = bx * 2048;
#pragma unroll
        for (int i = 0; i < 8; ++i) {
            int e = e0 + tid + i * 256;
            if (e < N_EDGES) {
                int s = src[e], d = dst[e];
                int g = grp[s];
                bkt[i] = d >> 9;
                ent[i] = s | (g << 17) | ((d & 511) << 18);
                rnk[i] = atomicAdd(&hist[bkt[i]], 1);
            } else {
                bkt[i] = -1;
            }
        }
        __syncthreads();
        for (int b = tid; b < NB; b += 256) {
            int hc = hist[b];
            gbase[b] = hc ? atomicAdd(&bcnt[b * NR + r], hc) : 0;
        }
        __syncthreads();
#pragma unroll
        for (int i = 0; i < 8; ++i) {
            if (bkt[i] >= 0) {
                int pos = gbase[bkt[i]] + rnk[i];
                if (pos < CAPB_R)
                    buckets[(bkt[i] * NR + r) * CAPB_R + pos] = ent[i];
            }
        }
    } else if (bx < NBB + 12500) {
        // ---- transcode h -> X[:,0:32] ----
        int i = (bx - NBB) * 256 + tid;          // pair index over N*32
        int n = i >> 5, c = i & 31;
        float2 v = reinterpret_cast<const float2*>(h)[i];
        X[(size_t)n * 96 + c] = pk_bf16(v.x, v.y);
    } else {
        // ---- Wcomb bf16 [64][192] = [W_self | W0 | W1] ----
        for (int idx = tid; idx < 6144; idx += 256) {
            int j = idx / 96, kk = idx - j * 96;
            int k = kk * 2;
            float lo, hi;
            if (k < 64)       { lo = W_self[j * 64 + k];          hi = W_self[j * 64 + k + 1]; }
            else if (k < 128) { lo = W_groups[j * 64 + k - 64];   hi = W_groups[j * 64 + k - 63]; }
            else              { lo = W_groups[4096 + j * 64 + k - 128];
                                hi = W_groups[4096 + j * 64 + k - 127]; }
            Wc[j * 96 + kk] = pk_bf16(lo, hi);
        }
    }
}

// ---------------------------------------------------------------------------
// Gather: block = 32 nodes, grid 3136 (12.2 blocks/CU; 8.3 KB LDS ->
// wave-capped 8 blocks/CU = 100% occupancy ceiling). Group-sorted dual-ended
// LDS CSR stores PRE-MULTIPLIED src*96 -> accumulate loop is add+load only.
// Full chunks touch only written slots (no predication). Tail chunks
// PREDICATE THE OFFSET (not just the accumulate): unwritten lcsr slots hold
// garbage that must never form an address (R7 crash lesson).
// ---------------------------------------------------------------------------
__global__ __launch_bounds__(256) void gather(u32* X,
                                              const int* __restrict__ bcnt,
                                              const int* __restrict__ buckets) {
    __shared__ int lcsr[32 * LCAP];   // 8 KB
    __shared__ int cnt0[32];
    __shared__ int cnt1[32];

    const int tid = threadIdx.x;
    const int cb = blockIdx.x >> 4;
    const int sub = blockIdx.x & 15;
    const int nbase = cb * 512 + sub * 32;
    if (nbase >= N_NODES) return;     // uniform early-out (before barriers)

    if (tid < 32) { cnt0[tid] = 0; cnt1[tid] = 0; }
    __syncthreads();

    for (int r = 0; r < NR; ++r) {
        const int cnt = min(bcnt[cb * NR + r], CAPB_R);
        const int* bp = buckets + (cb * NR + r) * CAPB_R;
        for (int i = tid; i < cnt; i += 256) {
            int e = bp[i];
            if (((e >> 23) & 15) == sub) {
                int nl = (e >> 18) & 31;
                int off = (e & SRC_MASK) * 96;   // pre-multiplied row offset
                if ((e >> 17) & 1) {
                    int s1 = atomicAdd(&cnt1[nl], 1);
                    if (s1 < LCAP) lcsr[nl * LCAP + (LCAP - 1 - s1)] = off;
                } else {
                    int s0 = atomicAdd(&cnt0[nl], 1);
                    if (s0 < LCAP) lcsr[nl * LCAP + s0] = off;
                }
            }
        }
    }
    __syncthreads();

    const int wave = tid >> 6;
    const int lane = tid & 63;
    const int half = lane >> 5;       // which edge of the pair
    const int c = lane & 31;          // channel-pair index

    for (int q = 0; q < 8; ++q) {
        const int nl = wave * 8 + q;
        const int n = nbase + nl;
        if (n >= N_NODES) continue;   // wave-uniform

        const int c0 = min(cnt0[nl], LCAP);
        const int c1 = min(cnt1[nl], LCAP);
        const int full0 = c0 & ~7;
        const int full1 = c1 & ~7;
        float a0l = 0.f, a0h = 0.f, a1l = 0.f, a1h = 0.f;

        // group 0: full chunks (no predication), then masked tail
        for (int i = 0; i < full0; i += 8) {
#pragma unroll
            for (int k = 0; k < 4; ++k) {
                int off = lcsr[nl * LCAP + i + 2 * k + half];
                u32 v = X[(size_t)off + c];
                a0l += __uint_as_float(v << 16);
                a0h += __uint_as_float(v & 0xffff0000u);
            }
        }
        if (full0 < c0) {
#pragma unroll
            for (int k = 0; k < 4; ++k) {
                int t = full0 + 2 * k + half;
                bool ok = t < c0;
                int off = ok ? lcsr[nl * LCAP + t] : 0;   // SAFE address
                u32 v = X[(size_t)off + c];
                a0l += ok ? __uint_as_float(v << 16) : 0.f;
                a0h += ok ? __uint_as_float(v & 0xffff0000u) : 0.f;
            }
        }
        // group 1 (stored from the back)
        for (int i = 0; i < full1; i += 8) {
#pragma unroll
            for (int k = 0; k < 4; ++k) {
                int off = lcsr[nl * LCAP + (LCAP - 1 - (i + 2 * k + half))];
                u32 v = X[(size_t)off + c];
                a1l += __uint_as_float(v << 16);
                a1h += __uint_as_float(v & 0xffff0000u);
            }
        }
        if (full1 < c1) {
#pragma unroll
            for (int k = 0; k < 4; ++k) {
                int t = full1 + 2 * k + half;
                bool ok = t < c1;
                int off = ok ? lcsr[nl * LCAP + (LCAP - 1 - t)] : 0;  // SAFE
                u32 v = X[(size_t)off + c];
                a1l += ok ? __uint_as_float(v << 16) : 0.f;
                a1h += ok ? __uint_as_float(v & 0xffff0000u) : 0.f;
            }
        }

        a0l += __shfl_xor(a0l, 32, 64);
        a0h += __shfl_xor(a0h, 32, 64);
        a1l += __shfl_xor(a1l, 32, 64);
        a1h += __shfl_xor(a1h, 32, 64);

        if (half == 0) {
            X[(size_t)n * 96 + 32 + c] = pk_bf16(a0l, a0h);   // group0 ch 2c,2c+1
            X[(size_t)n * 96 + 64 + c] = pk_bf16(a1l, a1h);   // group1 ch 2c,2c+1
        }
    }
}

// ---------------------------------------------------------------------------
// MFMA GEMM (unchanged from Round 6, verified): wave = 16 nodes x 64 j.
// ---------------------------------------------------------------------------
__global__ __launch_bounds__(256) void gemm_mfma(const u32* __restrict__ X,
                                                 const u32* __restrict__ Wc,
                                                 float* __restrict__ out) {
    const int tid = threadIdx.x;
    const int wave = tid >> 6;
    const int lane = tid & 63;
    const int m = lane & 15;
    const int quad = lane >> 4;
    const int n0 = blockIdx.x * 64 + wave * 16;

    int arow = n0 + m;
    if (arow > N_NODES - 1) arow = N_NODES - 1;   // load clamp (stores guarded)

    union Cvt { uint4 u; bfrag8 s; };

    bfrag8 a[6];
    const u32* ap = X + (size_t)arow * 96 + quad * 4;
#pragma unroll
    for (int ks = 0; ks < 6; ++ks) {
        Cvt cv;
        cv.u = *reinterpret_cast<const uint4*>(ap + ks * 16);
        a[ks] = cv.s;
    }

    f32x4 acc[4];
#pragma unroll
    for (int jt = 0; jt < 4; ++jt) acc[jt] = (f32x4){0.f, 0.f, 0.f, 0.f};

    const u32* wp = Wc + (size_t)m * 96 + quad * 4;
#pragma unroll
    for (int ks = 0; ks < 6; ++ks) {
#pragma unroll
        for (int jt = 0; jt < 4; ++jt) {
            Cvt cw;
            cw.u = *reinterpret_cast<const uint4*>(wp + jt * 1536 + ks * 16);
            acc[jt] = __builtin_amdgcn_mfma_f32_16x16x32_bf16(a[ks], cw.s, acc[jt], 0, 0, 0);
        }
    }

    const int rbase = n0 + quad * 4;
#pragma unroll
    for (int jt = 0; jt < 4; ++jt) {
#pragma unroll
        for (int r = 0; r < 4; ++r) {
            int n = rbase + r;
            if (n < N_NODES)
                out[(size_t)n * 64 + jt * 16 + m] = acc[jt][r];
        }
    }
}

extern "C" void kernel_launch(void* const* d_in, const int* in_sizes, int n_in,
                              void* d_out, int out_size, void* d_ws, size_t ws_size,
                              hipStream_t stream) {
    const float* h        = (const float*)d_in[0];
    const float* W_self   = (const float*)d_in[1];
    const float* W_groups = (const float*)d_in[2];
    const int*   src      = (const int*)d_in[3];
    const int*   dst      = (const int*)d_in[4];
    const int*   grp      = (const int*)d_in[5];
    float*       out      = (float*)d_out;

    int* bcnt    = (int*)d_ws;                          // 2048 ints (8 KB)
    int* buckets = bcnt + 2048;                         // NB*NR*CAPB_R ints
    u32* X       = (u32*)(buckets + NB * NR * CAPB_R);  // [N][96] u32, 38.4 MB
    u32* Wc      = X + (size_t)N_NODES * 96;            // [64][96] u32, 24.6 KB

    hipMemsetAsync(bcnt, 0, NB * NR * sizeof(int), stream);

    prep<<<NBB + 12500 + 1, 256, 0, stream>>>(h, W_self, W_groups, src, dst, grp,
                                              bcnt, buckets, X, Wc);
    gather<<<NB * 16, 256, 0, stream>>>(X, bcnt, buckets);
    gemm_mfma<<<(N_NODES + 63) / 64, 256, 0, stream>>>(X, Wc, out);
}

// Round 9
// 193.261 us; speedup vs baseline: 1.1091x; 1.1091x over previous
//
#include <hip/hip_runtime.h>

#define N_NODES 100000
#define N_EDGES 1600000
#define D 64
#define NB 392            // coarse buckets: nodes >> 8 (256 nodes each)
#define NR 8              // tail replicas per bucket (r = blockIdx&7)
#define CAPB_R 672        // per-(bucket,replica) capacity: mean 510, +7 sd
#define LCAP 64           // per-node LDS CSR slots (dual-ended)
#define SRC_MASK 0x1FFFF  // 17 bits
#define NBB 782           // bucket-phase blocks in prep kernel

typedef unsigned int u32;
typedef short bfrag8 __attribute__((ext_vector_type(8)));   // 8 bf16 (4 VGPRs)
typedef float f32x4 __attribute__((ext_vector_type(4)));    // MFMA accumulator

// Workspace (~46.9 MB <= proven 51.2 MB):
//   bcnt:    int[4096]               16 KB    (first NB*NR=3136 used; zeroed)
//   buckets: int[NB*NR*CAPB_R]       8.43 MB  entry = src | g<<17 | (d&255)<<18
//   X:       u32[N_NODES*96]        38.4 MB   packed bf16 pairs:
//              cols 0..31 = h, 32..63 = seg group0, 64..95 = seg group1
//   Wc:      u32[64*96]             24.6 KB   packed bf16 Wcomb[j][k]

__device__ inline u32 pk_bf16(float lo, float hi) {
    u32 a = __float_as_uint(lo);
    a = (a + 0x7fffu + ((a >> 16) & 1u)) >> 16;
    u32 b = __float_as_uint(hi);
    b = (b + 0x7fffu + ((b >> 16) & 1u)) & 0xffff0000u;
    return a | b;
}

// ---------------------------------------------------------------------------
// Fused prep: blocks [0,782) bucket edges; [782, 13282) transcode h -> X;
// block 13282 builds Wcomb.
// ---------------------------------------------------------------------------
__global__ __launch_bounds__(256) void prep(const float* __restrict__ h,
                                            const float* __restrict__ W_self,
                                            const float* __restrict__ W_groups,
                                            const int* __restrict__ src,
                                            const int* __restrict__ dst,
                                            const int* __restrict__ grp,
                                            int* __restrict__ bcnt,
                                            int* __restrict__ buckets,
                                            u32* __restrict__ X,
                                            u32* __restrict__ Wc) {
    __shared__ int hist[NB];
    __shared__ int gbase[NB];
    const int tid = threadIdx.x;
    const int bx = blockIdx.x;

    if (bx < NBB) {
        // ---- bucket phase ----
        const int r = bx & (NR - 1);
        for (int b = tid; b < NB; b += 256) hist[b] = 0;
        __syncthreads();

        int ent[8], bkt[8], rnk[8];
        const int e0 = bx * 2048;
#pragma unroll
        for (int i = 0; i < 8; ++i) {
            int e = e0 + tid + i * 256;
            if (e < N_EDGES) {
                int s = src[e], d = dst[e];
                int g = grp[s];
                bkt[i] = d >> 8;
                ent[i] = s | (g << 17) | ((d & 255) << 18);
                rnk[i] = atomicAdd(&hist[bkt[i]], 1);
            } else {
                bkt[i] = -1;
            }
        }
        __syncthreads();
        for (int b = tid; b < NB; b += 256) {
            int hc = hist[b];
            gbase[b] = hc ? atomicAdd(&bcnt[b * NR + r], hc) : 0;
        }
        __syncthreads();
#pragma unroll
        for (int i = 0; i < 8; ++i) {
            if (bkt[i] >= 0) {
                int pos = gbase[bkt[i]] + rnk[i];
                if (pos < CAPB_R)
                    buckets[(bkt[i] * NR + r) * CAPB_R + pos] = ent[i];
            }
        }
    } else if (bx < NBB + 12500) {
        // ---- transcode h -> X[:,0:32] ----
        int i = (bx - NBB) * 256 + tid;          // pair index over N*32
        int n = i >> 5, c = i & 31;
        float2 v = reinterpret_cast<const float2*>(h)[i];
        X[(size_t)n * 96 + c] = pk_bf16(v.x, v.y);
    } else {
        // ---- Wcomb bf16 [64][192] = [W_self | W0 | W1] ----
        for (int idx = tid; idx < 6144; idx += 256) {
            int j = idx / 96, kk = idx - j * 96;
            int k = kk * 2;
            float lo, hi;
            if (k < 64)       { lo = W_self[j * 64 + k];          hi = W_self[j * 64 + k + 1]; }
            else if (k < 128) { lo = W_groups[j * 64 + k - 64];   hi = W_groups[j * 64 + k - 63]; }
            else              { lo = W_groups[4096 + j * 64 + k - 128];
                                hi = W_groups[4096 + j * 64 + k - 127]; }
            Wc[j * 96 + kk] = pk_bf16(lo, hi);
        }
    }
}

// ---------------------------------------------------------------------------
// Gather: block = 64 nodes, grid 1568. Scan acceptance 1/4 (scan bytes
// 25.6 MB total, was 102 MB at 1/16 — the R8 regression lesson).
// Group-sorted dual-ended LDS CSR of pre-multiplied src*96 offsets.
// Interleaved g0/g1 full-chunk loop: 8 independent X loads in flight.
// Tail chunks predicate the OFFSET (R7 crash lesson).
// ---------------------------------------------------------------------------
__global__ __launch_bounds__(256) void gather(u32* X,
                                              const int* __restrict__ bcnt,
                                              const int* __restrict__ buckets) {
    __shared__ int lcsr[64 * LCAP];   // 16 KB
    __shared__ int cnt0[64];
    __shared__ int cnt1[64];

    const int tid = threadIdx.x;
    const int cb = blockIdx.x >> 2;   // coarse bucket
    const int sub = blockIdx.x & 3;   // 64-node sub-range
    const int nbase = cb * 256 + sub * 64;
    if (nbase >= N_NODES) return;     // uniform early-out (before barriers)

    if (tid < 64) { cnt0[tid] = 0; cnt1[tid] = 0; }
    __syncthreads();

    for (int r = 0; r < NR; ++r) {
        const int cnt = min(bcnt[cb * NR + r], CAPB_R);
        const int* bp = buckets + (cb * NR + r) * CAPB_R;
        for (int i = tid; i < cnt; i += 256) {
            int e = bp[i];
            if (((e >> 24) & 3) == sub) {
                int nl = (e >> 18) & 63;
                int off = (e & SRC_MASK) * 96;   // pre-multiplied row offset
                if ((e >> 17) & 1) {
                    int s1 = atomicAdd(&cnt1[nl], 1);
                    if (s1 < LCAP) lcsr[nl * LCAP + (LCAP - 1 - s1)] = off;
                } else {
                    int s0 = atomicAdd(&cnt0[nl], 1);
                    if (s0 < LCAP) lcsr[nl * LCAP + s0] = off;
                }
            }
        }
    }
    __syncthreads();

    const int wave = tid >> 6;
    const int lane = tid & 63;
    const int half = lane >> 5;       // which edge of the pair
    const int c = lane & 31;          // channel-pair index

    for (int q = 0; q < 16; ++q) {
        const int nl = wave * 16 + q;
        const int n = nbase + nl;
        if (n >= N_NODES) continue;   // wave-uniform

        const int c0 = min(cnt0[nl], LCAP);
        const int c1 = min(cnt1[nl], LCAP);
        float a0l = 0.f, a0h = 0.f, a1l = 0.f, a1h = 0.f;

        int i0 = 0, i1 = 0;
        // interleaved full chunks: 8 independent loads in flight
        for (; i0 + 8 <= c0 && i1 + 8 <= c1; i0 += 8, i1 += 8) {
            int offA[4], offB[4];
#pragma unroll
            for (int k = 0; k < 4; ++k) {
                offA[k] = lcsr[nl * LCAP + i0 + 2 * k + half];
                offB[k] = lcsr[nl * LCAP + (LCAP - 1 - (i1 + 2 * k + half))];
            }
            u32 vA[4], vB[4];
#pragma unroll
            for (int k = 0; k < 4; ++k) {
                vA[k] = X[(size_t)offA[k] + c];
                vB[k] = X[(size_t)offB[k] + c];
            }
#pragma unroll
            for (int k = 0; k < 4; ++k) {
                a0l += __uint_as_float(vA[k] << 16);
                a0h += __uint_as_float(vA[k] & 0xffff0000u);
                a1l += __uint_as_float(vB[k] << 16);
                a1h += __uint_as_float(vB[k] & 0xffff0000u);
            }
        }
        // remaining g0 full chunks
        for (; i0 + 8 <= c0; i0 += 8) {
#pragma unroll
            for (int k = 0; k < 4; ++k) {
                int off = lcsr[nl * LCAP + i0 + 2 * k + half];
                u32 v = X[(size_t)off + c];
                a0l += __uint_as_float(v << 16);
                a0h += __uint_as_float(v & 0xffff0000u);
            }
        }
        // remaining g1 full chunks
        for (; i1 + 8 <= c1; i1 += 8) {
#pragma unroll
            for (int k = 0; k < 4; ++k) {
                int off = lcsr[nl * LCAP + (LCAP - 1 - (i1 + 2 * k + half))];
                u32 v = X[(size_t)off + c];
                a1l += __uint_as_float(v << 16);
                a1h += __uint_as_float(v & 0xffff0000u);
            }
        }
        // tails: predicate the OFFSET (unwritten slots hold garbage)
        if (i0 < c0) {
#pragma unroll
            for (int k = 0; k < 4; ++k) {
                int t = i0 + 2 * k + half;
                bool ok = t < c0;
                int off = ok ? lcsr[nl * LCAP + t] : 0;
                u32 v = X[(size_t)off + c];
                a0l += ok ? __uint_as_float(v << 16) : 0.f;
                a0h += ok ? __uint_as_float(v & 0xffff0000u) : 0.f;
            }
        }
        if (i1 < c1) {
#pragma unroll
            for (int k = 0; k < 4; ++k) {
                int t = i1 + 2 * k + half;
                bool ok = t < c1;
                int off = ok ? lcsr[nl * LCAP + (LCAP - 1 - t)] : 0;
                u32 v = X[(size_t)off + c];
                a1l += ok ? __uint_as_float(v << 16) : 0.f;
                a1h += ok ? __uint_as_float(v & 0xffff0000u) : 0.f;
            }
        }

        a0l += __shfl_xor(a0l, 32, 64);
        a0h += __shfl_xor(a0h, 32, 64);
        a1l += __shfl_xor(a1l, 32, 64);
        a1h += __shfl_xor(a1h, 32, 64);

        if (half == 0) {
            X[(size_t)n * 96 + 32 + c] = pk_bf16(a0l, a0h);   // group0 ch 2c,2c+1
            X[(size_t)n * 96 + 64 + c] = pk_bf16(a1l, a1h);   // group1 ch 2c,2c+1
        }
    }
}

// ---------------------------------------------------------------------------
// MFMA GEMM (unchanged, verified): wave = 16 nodes x 64 j.
// ---------------------------------------------------------------------------
__global__ __launch_bounds__(256) void gemm_mfma(const u32* __restrict__ X,
                                                 const u32* __restrict__ Wc,
                                                 float* __restrict__ out) {
    const int tid = threadIdx.x;
    const int wave = tid >> 6;
    const int lane = tid & 63;
    const int m = lane & 15;
    const int quad = lane >> 4;
    const int n0 = blockIdx.x * 64 + wave * 16;

    int arow = n0 + m;
    if (arow > N_NODES - 1) arow = N_NODES - 1;   // load clamp (stores guarded)

    union Cvt { uint4 u; bfrag8 s; };

    bfrag8 a[6];
    const u32* ap = X + (size_t)arow * 96 + quad * 4;
#pragma unroll
    for (int ks = 0; ks < 6; ++ks) {
        Cvt cv;
        cv.u = *reinterpret_cast<const uint4*>(ap + ks * 16);
        a[ks] = cv.s;
    }

    f32x4 acc[4];
#pragma unroll
    for (int jt = 0; jt < 4; ++jt) acc[jt] = (f32x4){0.f, 0.f, 0.f, 0.f};

    const u32* wp = Wc + (size_t)m * 96 + quad * 4;
#pragma unroll
    for (int ks = 0; ks < 6; ++ks) {
#pragma unroll
        for (int jt = 0; jt < 4; ++jt) {
            Cvt cw;
            cw.u = *reinterpret_cast<const uint4*>(wp + jt * 1536 + ks * 16);
            acc[jt] = __builtin_amdgcn_mfma_f32_16x16x32_bf16(a[ks], cw.s, acc[jt], 0, 0, 0);
        }
    }

    const int rbase = n0 + quad * 4;
#pragma unroll
    for (int jt = 0; jt < 4; ++jt) {
#pragma unroll
        for (int r = 0; r < 4; ++r) {
            int n = rbase + r;
            if (n < N_NODES)
                out[(size_t)n * 64 + jt * 16 + m] = acc[jt][r];
        }
    }
}

extern "C" void kernel_launch(void* const* d_in, const int* in_sizes, int n_in,
                              void* d_out, int out_size, void* d_ws, size_t ws_size,
                              hipStream_t stream) {
    const float* h        = (const float*)d_in[0];
    const float* W_self   = (const float*)d_in[1];
    const float* W_groups = (const float*)d_in[2];
    const int*   src      = (const int*)d_in[3];
    const int*   dst      = (const int*)d_in[4];
    const int*   grp      = (const int*)d_in[5];
    float*       out      = (float*)d_out;

    int* bcnt    = (int*)d_ws;                          // 4096 ints (16 KB)
    int* buckets = bcnt + 4096;                         // NB*NR*CAPB_R ints
    u32* X       = (u32*)(buckets + NB * NR * CAPB_R);  // [N][96] u32, 38.4 MB
    u32* Wc      = X + (size_t)N_NODES * 96;            // [64][96] u32, 24.6 KB

    hipMemsetAsync(bcnt, 0, NB * NR * sizeof(int), stream);

    prep<<<NBB + 12500 + 1, 256, 0, stream>>>(h, W_self, W_groups, src, dst, grp,
                                              bcnt, buckets, X, Wc);
    gather<<<NB * 4, 256, 0, stream>>>(X, bcnt, buckets);
    gemm_mfma<<<(N_NODES + 63) / 64, 256, 0, stream>>>(X, Wc, out);
}

// Round 10
// 185.611 us; speedup vs baseline: 1.1548x; 1.0412x over previous
//
#include <hip/hip_runtime.h>

#define N_NODES 100000
#define N_EDGES 1600000
#define D 64
#define NB 784            // coarse buckets: nodes >> 7 (128 nodes each)
#define NR 8              // tail replicas per bucket (r = blockIdx&7)
#define CAPB_R 384        // per-(bucket,replica) capacity: mean 256, +8 sd
#define LCAP 64           // per-node LDS CSR slots (dual-ended)
#define SRC_MASK 0x1FFFF  // 17 bits
#define NBB 782           // bucket-phase blocks in prep kernel

typedef unsigned int u32;
typedef short bfrag8 __attribute__((ext_vector_type(8)));   // 8 bf16 (4 VGPRs)
typedef float f32x4 __attribute__((ext_vector_type(4)));    // MFMA accumulator

// Workspace (~22.5 MB <= proven 51.2 MB):
//   bcnt:    int[8192]               32 KB    (first NB*NR=6272 used; zeroed)
//   buckets: int[NB*NR*CAPB_R]       9.63 MB  entry = src | g<<17 | (d&127)<<18
//   h_bf:    u32[N_NODES*32]        12.8 MB   packed bf16 channel pairs
//   Wc:      u32[64*96]             24.6 KB   packed bf16 Wcomb[j][k]

__device__ inline u32 pk_bf16(float lo, float hi) {
    u32 a = __float_as_uint(lo);
    a = (a + 0x7fffu + ((a >> 16) & 1u)) >> 16;
    u32 b = __float_as_uint(hi);
    b = (b + 0x7fffu + ((b >> 16) & 1u)) & 0xffff0000u;
    return a | b;
}

// ---------------------------------------------------------------------------
// Fused prep: blocks [0,782) bucket edges; [782, 13282) transcode h -> h_bf
// (fully contiguous now); block 13282 builds Wcomb.
// ---------------------------------------------------------------------------
__global__ __launch_bounds__(256) void prep(const float* __restrict__ h,
                                            const float* __restrict__ W_self,
                                            const float* __restrict__ W_groups,
                                            const int* __restrict__ src,
                                            const int* __restrict__ dst,
                                            const int* __restrict__ grp,
                                            int* __restrict__ bcnt,
                                            int* __restrict__ buckets,
                                            u32* __restrict__ h_bf,
                                            u32* __restrict__ Wc) {
    __shared__ int hist[NB];
    __shared__ int gbase[NB];
    const int tid = threadIdx.x;
    const int bx = blockIdx.x;

    if (bx < NBB) {
        // ---- bucket phase ----
        const int r = bx & (NR - 1);
        for (int b = tid; b < NB; b += 256) hist[b] = 0;
        __syncthreads();

        int ent[8], bkt[8], rnk[8];
        const int e0 = bx * 2048;
#pragma unroll
        for (int i = 0; i < 8; ++i) {
            int e = e0 + tid + i * 256;
            if (e < N_EDGES) {
                int s = src[e], d = dst[e];
                int g = grp[s];
                bkt[i] = d >> 7;
                ent[i] = s | (g << 17) | ((d & 127) << 18);
                rnk[i] = atomicAdd(&hist[bkt[i]], 1);
            } else {
                bkt[i] = -1;
            }
        }
        __syncthreads();
        for (int b = tid; b < NB; b += 256) {
            int hc = hist[b];
            gbase[b] = hc ? atomicAdd(&bcnt[b * NR + r], hc) : 0;
        }
        __syncthreads();
#pragma unroll
        for (int i = 0; i < 8; ++i) {
            if (bkt[i] >= 0) {
                int pos = gbase[bkt[i]] + rnk[i];
                if (pos < CAPB_R)
                    buckets[(bkt[i] * NR + r) * CAPB_R + pos] = ent[i];
            }
        }
    } else if (bx < NBB + 12500) {
        // ---- transcode h -> h_bf (contiguous) ----
        int i = (bx - NBB) * 256 + tid;
        float2 v = reinterpret_cast<const float2*>(h)[i];
        h_bf[i] = pk_bf16(v.x, v.y);
    } else {
        // ---- Wcomb bf16 [64][192] = [W_self | W0 | W1] ----
        for (int idx = tid; idx < 6144; idx += 256) {
            int j = idx / 96, kk = idx - j * 96;
            int k = kk * 2;
            float lo, hi;
            if (k < 64)       { lo = W_self[j * 64 + k];          hi = W_self[j * 64 + k + 1]; }
            else if (k < 128) { lo = W_groups[j * 64 + k - 64];   hi = W_groups[j * 64 + k - 63]; }
            else              { lo = W_groups[4096 + j * 64 + k - 128];
                                hi = W_groups[4096 + j * 64 + k - 127]; }
            Wc[j * 96 + kk] = pk_bf16(lo, hi);
        }
    }
}

// ---------------------------------------------------------------------------
// Fused gather + MFMA GEMM. Block = 64 nodes, grid 1568 (scan acceptance
// 1/2 -> 12.8 MB total scan).
// Phase 1: group-sorted dual-ended LDS CSR of pre-multiplied src*32 offsets.
// Phase 2: R9 accumulate loop; results written IN PLACE into the node's own
//   (now dead) lcsr row as packed bf16: [s0 pairs 0..31 | s1 pairs 0..31].
// Phase 3: per-wave MFMA over its own 16 rows: A = [h cols (global) |
//   s0,s1 (LDS row)], B = Wc (L1-resident), D -> out. No seg buffer, no
//   separate gemm kernel, no X re-read.
// ---------------------------------------------------------------------------
__global__ __launch_bounds__(256) void gather_gemm(const u32* __restrict__ h_bf,
                                                   const int* __restrict__ bcnt,
                                                   const int* __restrict__ buckets,
                                                   const u32* __restrict__ Wc,
                                                   float* __restrict__ out) {
    __shared__ __align__(16) int lcsr[64 * LCAP];   // 16 KB
    __shared__ int cnt0[64];
    __shared__ int cnt1[64];

    const int tid = threadIdx.x;
    const int cb = blockIdx.x >> 1;   // coarse bucket (128 nodes)
    const int sub = blockIdx.x & 1;   // 64-node sub-range
    const int nbase = cb * 128 + sub * 64;
    if (nbase >= N_NODES) return;     // uniform early-out (before barriers)

    if (tid < 64) { cnt0[tid] = 0; cnt1[tid] = 0; }
    __syncthreads();

    // ---- Phase 1: CSR build ----
    for (int r = 0; r < NR; ++r) {
        const int cnt = min(bcnt[cb * NR + r], CAPB_R);
        const int* bp = buckets + (cb * NR + r) * CAPB_R;
        for (int i = tid; i < cnt; i += 256) {
            int e = bp[i];
            if (((e >> 24) & 1) == sub) {
                int nl = (e >> 18) & 63;
                int off = (e & SRC_MASK) * 32;   // pre-multiplied row offset
                if ((e >> 17) & 1) {
                    int s1 = atomicAdd(&cnt1[nl], 1);
                    if (s1 < LCAP) lcsr[nl * LCAP + (LCAP - 1 - s1)] = off;
                } else {
                    int s0 = atomicAdd(&cnt0[nl], 1);
                    if (s0 < LCAP) lcsr[nl * LCAP + s0] = off;
                }
            }
        }
    }
    __syncthreads();

    const int wave = tid >> 6;
    const int lane = tid & 63;
    const int half = lane >> 5;       // which edge of the pair
    const int c = lane & 31;          // channel-pair index

    // ---- Phase 2: accumulate; write results in place into lcsr row ----
    for (int q = 0; q < 16; ++q) {
        const int nl = wave * 16 + q;
        const int n = nbase + nl;
        if (n >= N_NODES) continue;   // wave-uniform

        const int c0 = min(cnt0[nl], LCAP);
        const int c1 = min(cnt1[nl], LCAP);
        float a0l = 0.f, a0h = 0.f, a1l = 0.f, a1h = 0.f;

        int i0 = 0, i1 = 0;
        for (; i0 + 8 <= c0 && i1 + 8 <= c1; i0 += 8, i1 += 8) {
            int offA[4], offB[4];
#pragma unroll
            for (int k = 0; k < 4; ++k) {
                offA[k] = lcsr[nl * LCAP + i0 + 2 * k + half];
                offB[k] = lcsr[nl * LCAP + (LCAP - 1 - (i1 + 2 * k + half))];
            }
            u32 vA[4], vB[4];
#pragma unroll
            for (int k = 0; k < 4; ++k) {
                vA[k] = h_bf[(size_t)offA[k] + c];
                vB[k] = h_bf[(size_t)offB[k] + c];
            }
#pragma unroll
            for (int k = 0; k < 4; ++k) {
                a0l += __uint_as_float(vA[k] << 16);
                a0h += __uint_as_float(vA[k] & 0xffff0000u);
                a1l += __uint_as_float(vB[k] << 16);
                a1h += __uint_as_float(vB[k] & 0xffff0000u);
            }
        }
        for (; i0 + 8 <= c0; i0 += 8) {
#pragma unroll
            for (int k = 0; k < 4; ++k) {
                int off = lcsr[nl * LCAP + i0 + 2 * k + half];
                u32 v = h_bf[(size_t)off + c];
                a0l += __uint_as_float(v << 16);
                a0h += __uint_as_float(v & 0xffff0000u);
            }
        }
        for (; i1 + 8 <= c1; i1 += 8) {
#pragma unroll
            for (int k = 0; k < 4; ++k) {
                int off = lcsr[nl * LCAP + (LCAP - 1 - (i1 + 2 * k + half))];
                u32 v = h_bf[(size_t)off + c];
                a1l += __uint_as_float(v << 16);
                a1h += __uint_as_float(v & 0xffff0000u);
            }
        }
        if (i0 < c0) {
#pragma unroll
            for (int k = 0; k < 4; ++k) {
                int t = i0 + 2 * k + half;
                bool ok = t < c0;
                int off = ok ? lcsr[nl * LCAP + t] : 0;   // SAFE address
                u32 v = h_bf[(size_t)off + c];
                a0l += ok ? __uint_as_float(v << 16) : 0.f;
                a0h += ok ? __uint_as_float(v & 0xffff0000u) : 0.f;
            }
        }
        if (i1 < c1) {
#pragma unroll
            for (int k = 0; k < 4; ++k) {
                int t = i1 + 2 * k + half;
                bool ok = t < c1;
                int off = ok ? lcsr[nl * LCAP + (LCAP - 1 - t)] : 0;  // SAFE
                u32 v = h_bf[(size_t)off + c];
                a1l += ok ? __uint_as_float(v << 16) : 0.f;
                a1h += ok ? __uint_as_float(v & 0xffff0000u) : 0.f;
            }
        }

        a0l += __shfl_xor(a0l, 32, 64);
        a0h += __shfl_xor(a0h, 32, 64);
        a1l += __shfl_xor(a1l, 32, 64);
        a1h += __shfl_xor(a1h, 32, 64);

        // Row nl of lcsr is dead now -> reuse it as the seg tile (in-order
        // per-wave DS semantics make the read-before-write safe).
        if (half == 0) {
            lcsr[nl * LCAP + c]      = (int)pk_bf16(a0l, a0h);  // s0 ch 2c,2c+1
            lcsr[nl * LCAP + 32 + c] = (int)pk_bf16(a1l, a1h);  // s1 ch 2c,2c+1
        }
    }
    __syncthreads();

    // ---- Phase 3: MFMA over this wave's own 16 rows ----
    const int m = lane & 15;
    const int quad = lane >> 4;
    const int nl16 = wave * 16 + m;
    const int arow = nbase + nl16;
    const int ar = (arow < N_NODES) ? arow : (N_NODES - 1);  // load clamp

    union Cvt { uint4 u; bfrag8 s; };
    bfrag8 a[6];
    const u32* ap = h_bf + (size_t)ar * 32 + quad * 4;
#pragma unroll
    for (int ks = 0; ks < 2; ++ks) {             // k = 0..63: h columns
        Cvt cv;
        cv.u = *reinterpret_cast<const uint4*>(ap + ks * 16);
        a[ks] = cv.s;
    }
#pragma unroll
    for (int ks = 2; ks < 6; ++ks) {             // k = 64..191: s0|s1 from LDS
        Cvt cv;
        cv.u = *reinterpret_cast<const uint4*>(&lcsr[nl16 * LCAP + (ks - 2) * 16 + quad * 4]);
        a[ks] = cv.s;
    }

    f32x4 acc[4];
#pragma unroll
    for (int jt = 0; jt < 4; ++jt) acc[jt] = (f32x4){0.f, 0.f, 0.f, 0.f};

    const u32* wp = Wc + (size_t)m * 96 + quad * 4;
#pragma unroll
    for (int ks = 0; ks < 6; ++ks) {
#pragma unroll
        for (int jt = 0; jt < 4; ++jt) {
            Cvt cw;
            cw.u = *reinterpret_cast<const uint4*>(wp + jt * 1536 + ks * 16);
            acc[jt] = __builtin_amdgcn_mfma_f32_16x16x32_bf16(a[ks], cw.s, acc[jt], 0, 0, 0);
        }
    }

    const int rbase = nbase + wave * 16 + quad * 4;
#pragma unroll
    for (int jt = 0; jt < 4; ++jt) {
#pragma unroll
        for (int r = 0; r < 4; ++r) {
            int n = rbase + r;
            if (n < N_NODES)
                out[(size_t)n * 64 + jt * 16 + m] = acc[jt][r];
        }
    }
}

extern "C" void kernel_launch(void* const* d_in, const int* in_sizes, int n_in,
                              void* d_out, int out_size, void* d_ws, size_t ws_size,
                              hipStream_t stream) {
    const float* h        = (const float*)d_in[0];
    const float* W_self   = (const float*)d_in[1];
    const float* W_groups = (const float*)d_in[2];
    const int*   src      = (const int*)d_in[3];
    const int*   dst      = (const int*)d_in[4];
    const int*   grp      = (const int*)d_in[5];
    float*       out      = (float*)d_out;

    int* bcnt    = (int*)d_ws;                          // 8192 ints (32 KB)
    int* buckets = bcnt + 8192;                         // NB*NR*CAPB_R ints
    u32* h_bf    = (u32*)(buckets + NB * NR * CAPB_R);  // [N][32] u32, 12.8 MB
    u32* Wc      = h_bf + (size_t)N_NODES * 32;         // [64][96] u32, 24.6 KB

    hipMemsetAsync(bcnt, 0, NB * NR * sizeof(int), stream);

    prep<<<NBB + 12500 + 1, 256, 0, stream>>>(h, W_self, W_groups, src, dst, grp,
                                              bcnt, buckets, h_bf, Wc);
    gather_gemm<<<NB * 2, 256, 0, stream>>>(h_bf, bcnt, buckets, Wc, out);
}